// Round 3
// baseline (202.123 us; speedup 1.0000x reference)
//
#include <hip/hip_runtime.h>
#include <stdint.h>

#define N_  32
#define C_  128
#define H_  56
#define W_  56
#define HW_ 3136
#define P_  128

using i32x4 = __attribute__((ext_vector_type(4))) int;

// ws layout (bytes):
//   wI8 : P*1152 = 147,456  (i8 +1/-1 weights, [p][tap*128+c])
//   inv : P*4
//   b0  : P*4
#define WI8_BYTES (P_*1152)

// ------- pack weights to i8 +1/-1 in [p][t*128+c] layout; fold BN ------------
__global__ __launch_bounds__(256) void wpack_kernel(const float* __restrict__ weight,
        const float* __restrict__ bias, const float* __restrict__ gamma,
        const float* __restrict__ beta, const float* __restrict__ mean,
        const float* __restrict__ var,
        uint32_t* __restrict__ wI8, float* __restrict__ invG, float* __restrict__ b0G) {
    int gid = blockIdx.x * 256 + threadIdx.x;        // 144 blocks = 36864 dwords
    int p   = gid / 288;
    int rem = gid % 288;
    int k   = rem * 4;                               // k = t*128 + c
    int tp  = k >> 7;
    int c   = k & 127;
    uint32_t d = 0;
    #pragma unroll
    for (int i2 = 0; i2 < 4; ++i2) {
        float v = weight[((size_t)p * C_ + c + i2) * 9 + tp];
        uint32_t by = (v >= 0.f) ? 0x01u : 0xFFu;
        d |= by << (8 * i2);
    }
    wI8[gid] = d;
    if (blockIdx.x == 0 && threadIdx.x < P_) {
        int pp = threadIdx.x;
        float inv = gamma[pp] * rsqrtf(var[pp] + 1e-5f);
        invG[pp] = inv;
        b0G[pp]  = bias[pp] * inv + beta[pp] - mean[pp] * inv;
    }
}

// ------- fused: sign-binarize x in-kernel + binary conv via i8 MFMA + BN + res
// Block: 2 output rows x 64 cols x 128 out-ch.
// Occupancy design (R3): __launch_bounds__(256,4) -> 128 regs/wave total.
// acc = 64 AGPRs (unified file) leaves 64 arch VGPRs. To fit:
//   - expansion uses static scalar accumulation, <=16 result regs + short
//     load queue (R1's dwv[4][8]+hoisted loads needed ~100 -> spilled)
//   - weights single-buffered (16 regs, not 32); per-tap L2 latency (~250cy)
//     is hidden by 16 waves/CU TLP instead of the double-buffer.
// 4 blocks/CU * 35840B LDS = 143KB <= 160KB. Grid 896 <= capacity 1024:
// single occupancy round.
__global__ __launch_bounds__(256, 4) void bconv_kernel(
        const uint4* __restrict__ wI8v,
        const float* __restrict__ invG, const float* __restrict__ b0G,
        const float* __restrict__ x, float* __restrict__ out) {
    __shared__ uint4 actT[4 * 68 * 8];   // 34816 B: [rho][colL][cblk ^ (colL&7)]
    __shared__ float sInv[P_], sB0[P_];

    int tid = threadIdx.x;
    int img = blockIdx.x / 28;
    int rp  = blockIdx.x % 28;
    int r0  = rp * 2;

    int lane = tid & 63;
    int wi   = tid >> 6;
    int q    = lane >> 4;
    int l15  = lane & 15;
    int m0   = wi * 32;

    if (tid < P_) { sInv[tid] = invG[tid]; sB0[tid] = b0G[tid]; }

    // ---- expand x signs -> i8 tile (+1/-1, 0 outside image), swizzled ------
    // 224 workers: (rho 0..3) x (cg 0..3: 32-ch group) x (tq 0..13: 4 cols).
    // Two passes of 16 channels each; per pass, per dword d (4 channels),
    // accumulate sign bits into 4 per-cell scalars -> all indices static.
    if (tid < 224) {
        int rho = tid / 56;
        int rr  = tid % 56;
        int cg  = rr / 14;               // channel group: c = cg*32 + ci
        int tq  = rr % 14;               // wv0 = tq*4
        int h   = r0 - 1 + rho;
        bool vh = ((unsigned)h < (unsigned)H_);
        uint32_t c0 = vh ? 0x01010101u : 0u;   // invalid row -> all-zero bytes
        uint32_t cf = vh ? 0xFEu       : 0u;
        const uint32_t* xb = (const uint32_t*)x
            + ((size_t)img * C_ + cg * 32) * HW_ + h * W_ + tq * 4;
        int colL0 = tq * 4 + 1;                // cells colL 1..56 (wv 0..55)
        #pragma unroll
        for (int ph = 0; ph < 2; ++ph) {       // 16 channels per pass
            uint32_t cell0[4], cell1[4], cell2[4], cell3[4];
            #pragma unroll
            for (int d = 0; d < 4; ++d) {      // dword d = channels d*4..d*4+3
                uint32_t w0 = 0, w1 = 0, w2 = 0, w3 = 0;
                if (vh) {
                    #pragma unroll
                    for (int i = 0; i < 4; ++i) {
                        uint4 u = *(const uint4*)(xb + (size_t)(ph * 16 + d * 4 + i) * HW_);
                        uint32_t sh = i * 8;
                        w0 |= (u.x >> 31) << sh;
                        w1 |= (u.y >> 31) << sh;
                        w2 |= (u.z >> 31) << sh;
                        w3 |= (u.w >> 31) << sh;
                    }
                }
                cell0[d] = c0 + w0 * cf;
                cell1[d] = c0 + w1 * cf;
                cell2[d] = c0 + w2 * cf;
                cell3[d] = c0 + w3 * cf;
            }
            int cb = cg * 2 + ph;              // 16B chunk index (16 channels)
            actT[(rho * 68 + colL0 + 0) * 8 + (cb ^ ((colL0 + 0) & 7))] =
                make_uint4(cell0[0], cell0[1], cell0[2], cell0[3]);
            actT[(rho * 68 + colL0 + 1) * 8 + (cb ^ ((colL0 + 1) & 7))] =
                make_uint4(cell1[0], cell1[1], cell1[2], cell1[3]);
            actT[(rho * 68 + colL0 + 2) * 8 + (cb ^ ((colL0 + 2) & 7))] =
                make_uint4(cell2[0], cell2[1], cell2[2], cell2[3]);
            actT[(rho * 68 + colL0 + 3) * 8 + (cb ^ ((colL0 + 3) & 7))] =
                make_uint4(cell3[0], cell3[1], cell3[2], cell3[3]);
        }
    } else {
        // 32 threads zero the halo cells: colL==0 and colL 57..67, all 4 rows
        int z = tid - 224;
        #pragma unroll
        for (int rep = 0; rep < 2; ++rep) {
            int e = z + rep * 32;
            if (e < 48) {
                int rho  = e / 12;
                int jj   = e % 12;
                int colL = jj ? (56 + jj) : 0;
                int base = (rho * 68 + colL) * 8;
                #pragma unroll
                for (int s = 0; s < 8; ++s) actT[base + s] = make_uint4(0u,0u,0u,0u);
            }
        }
    }

    i32x4 acc[2][8];
    #pragma unroll
    for (int mi = 0; mi < 2; ++mi)
        #pragma unroll
        for (int j = 0; j < 8; ++j)
            #pragma unroll
            for (int e = 0; e < 4; ++e) acc[mi][j][e] = 0;

    __syncthreads();                     // the ONLY barrier

    for (int t9 = 0; t9 < 9; ++t9) {
        // single-buffered per-tap weights (16 arch regs); L2-hot, TLP-hidden
        i32x4 aw[2][2];                  // [mi][ks]
        #pragma unroll
        for (int mi = 0; mi < 2; ++mi)
            #pragma unroll
            for (int ks = 0; ks < 2; ++ks)
                aw[mi][ks] = *(const i32x4*)&wI8v[(size_t)(m0 + mi*16 + l15) * 72
                                                  + t9 * 8 + ks * 4 + q];
        int dh = t9 / 3, dw = t9 % 3;
        #pragma unroll
        for (int ks = 0; ks < 2; ++ks) {
            #pragma unroll
            for (int j = 0; j < 8; ++j) {
                int n    = j * 16 + l15;
                int colL = (n & 63) + dw;
                int rho  = (n >> 6) + dh;
                i32x4 bf = *(const i32x4*)&actT[(rho * 68 + colL) * 8 + ((ks * 4 + q) ^ (colL & 7))];
                acc[0][j] = __builtin_amdgcn_mfma_i32_16x16x64_i8(aw[0][ks], bf, acc[0][j], 0, 0, 0);
                acc[1][j] = __builtin_amdgcn_mfma_i32_16x16x64_i8(aw[1][ks], bf, acc[1][j], 0, 0, 0);
            }
        }
    }

    // ---- epilogue: BN + residual, coalesced 64B segments ----
    float invR[2][4], b0R[2][4];
    #pragma unroll
    for (int mi = 0; mi < 2; ++mi)
        #pragma unroll
        for (int reg = 0; reg < 4; ++reg) {
            int m = m0 + mi * 16 + q * 4 + reg;
            invR[mi][reg] = sInv[m];
            b0R[mi][reg]  = sB0[m];
        }
    #pragma unroll
    for (int j = 0; j < 8; ++j) {
        int n = j * 16 + l15;
        int w = n & 63;
        if (w < W_) {
            int orow = r0 + (n >> 6);
            size_t pixOff = (size_t)img * P_ * HW_ + (size_t)orow * W_ + w;
            #pragma unroll
            for (int mi = 0; mi < 2; ++mi)
                #pragma unroll
                for (int reg = 0; reg < 4; ++reg) {
                    int m = m0 + mi * 16 + q * 4 + reg;
                    size_t off = pixOff + (size_t)m * HW_;
                    out[off] = (float)acc[mi][j][reg] * invR[mi][reg] + b0R[mi][reg] + x[off];
                }
        }
    }
}

extern "C" void kernel_launch(void* const* d_in, const int* in_sizes, int n_in,
                              void* d_out, int out_size, void* d_ws, size_t ws_size,
                              hipStream_t stream) {
    const float* x      = (const float*)d_in[0];
    const float* weight = (const float*)d_in[1];
    const float* bias   = (const float*)d_in[2];
    const float* gamma  = (const float*)d_in[3];
    const float* beta   = (const float*)d_in[4];
    const float* mean   = (const float*)d_in[5];
    const float* var    = (const float*)d_in[6];
    float* out = (float*)d_out;

    uint8_t*  ws    = (uint8_t*)d_ws;
    uint32_t* wI8   = (uint32_t*)ws;
    float*    invG  = (float*)(ws + WI8_BYTES);
    float*    b0G   = invG + P_;

    wpack_kernel<<<144, 256, 0, stream>>>(weight, bias, gamma, beta, mean, var, wI8, invG, b0G);
    bconv_kernel<<<32 * 28, 256, 0, stream>>>((const uint4*)wI8, invG, b0G, x, out);
}

// Round 4
// 170.979 us; speedup vs baseline: 1.1822x; 1.1822x over previous
//
#include <hip/hip_runtime.h>
#include <stdint.h>

#define N_  32
#define C_  128
#define H_  56
#define W_  56
#define HW_ 3136
#define P_  128

using i32x4 = __attribute__((ext_vector_type(4))) int;

// ws layout (bytes):
//   wI8 : P*1152 = 147,456  (i8 +1/-1 weights, [p][tap*128+c])
//   inv : P*4
//   b0  : P*4
#define WI8_BYTES (P_*1152)

// ------- pack weights to i8 +1/-1 in [p][t*128+c] layout; fold BN ------------
__global__ __launch_bounds__(256) void wpack_kernel(const float* __restrict__ weight,
        const float* __restrict__ bias, const float* __restrict__ gamma,
        const float* __restrict__ beta, const float* __restrict__ mean,
        const float* __restrict__ var,
        uint32_t* __restrict__ wI8, float* __restrict__ invG, float* __restrict__ b0G) {
    int gid = blockIdx.x * 256 + threadIdx.x;        // 144 blocks = 36864 dwords
    int p   = gid / 288;
    int rem = gid % 288;
    int k   = rem * 4;                               // k = t*128 + c
    int tp  = k >> 7;
    int c   = k & 127;
    uint32_t d = 0;
    #pragma unroll
    for (int i2 = 0; i2 < 4; ++i2) {
        float v = weight[((size_t)p * C_ + c + i2) * 9 + tp];
        uint32_t by = (v >= 0.f) ? 0x01u : 0xFFu;
        d |= by << (8 * i2);
    }
    wI8[gid] = d;
    if (blockIdx.x == 0 && threadIdx.x < P_) {
        int pp = threadIdx.x;
        float inv = gamma[pp] * rsqrtf(var[pp] + 1e-5f);
        invG[pp] = inv;
        b0G[pp]  = bias[pp] * inv + beta[pp] - mean[pp] * inv;
    }
}

// ------- fused: sign-binarize x in-kernel + binary conv via i8 MFMA + BN + res
// R4 redesign: block = 2 rows x 32 cols x 128 out-ch  (was 2x64x128).
// Rationale: acc[2][8]=64 regs + 128-reg cap spilled catastrophically twice
// (R1/R3: WRITE_SIZE 234MB, MfmaUtil 0.08%). Halving the column tile gives
// acc[2][4]=32 regs, restores the weight double-buffer (R0's proven +11us),
// and leaves ~25 regs slack under __launch_bounds__(256,4) -> 16 waves/CU
// with NO allocator coercion. Grid 1792 finer blocks (tail quantization
// shrinks); act halo re-reads are L2-absorbed.
// Tripwire: if WRITE_SIZE >> 52MB it spilled again -> revert to (256) bounds.
__global__ __launch_bounds__(256, 4) void bconv_kernel(
        const uint4* __restrict__ wI8v,
        const float* __restrict__ invG, const float* __restrict__ b0G,
        const float* __restrict__ x, float* __restrict__ out) {
    __shared__ uint4 actT[4 * 34 * 8];   // 17,408 B: [rho][colL][cblk ^ (colL&7)]
    __shared__ float sInv[P_], sB0[P_];

    int tid = threadIdx.x;
    int bid = blockIdx.x;
    int img = bid / 56;                  // 56 tiles per image
    int rem = bid % 56;
    int r0  = (rem >> 1) * 2;            // row pair
    int c0  = (rem & 1) * 32;            // column half

    int lane = tid & 63;
    int wi   = tid >> 6;
    int q    = lane >> 4;
    int l15  = lane & 15;
    int m0   = wi * 32;

    if (tid < P_) { sInv[tid] = invG[tid]; sB0[tid] = b0G[tid]; }

    // ---- tap-0 weight prefetch (global, L2-hot) issued before expansion so
    // its latency hides under the expansion work; only aw[0] (16 regs) live.
    i32x4 aw[2][2][2];                   // [buf][mi][ks]
    #pragma unroll
    for (int mi = 0; mi < 2; ++mi)
        #pragma unroll
        for (int ks = 0; ks < 2; ++ks)
            aw[0][mi][ks] = *(const i32x4*)&wI8v[(size_t)(m0 + mi*16 + l15) * 72
                                                 + ks * 4 + q];

    // ---- expand x signs -> i8 tile (+1/-1, 0 outside image), swizzled ------
    // wave wi owns tile row rho=wi (h uniform per wave -> no divergence on vh).
    // 272 units = 8 chunk-groups x 34 cols; lane handles units lane, lane+64,
    // lane+128, lane+192 (+256 if lane<16). Per unit: 16 scalar 4B loads of
    // one pixel across 16 channels -> 1 swizzled uint4 store. ~16 live regs.
    {
        int rho = wi;
        int h   = r0 - 1 + rho;
        bool vh = ((unsigned)h < (unsigned)H_);
        const uint32_t* xrow = (const uint32_t*)x
            + (size_t)img * C_ * HW_ + (size_t)(vh ? h : 0) * W_;
        #pragma unroll
        for (int k = 0; k < 5; ++k) {
            int u = k * 64 + lane;
            if (u < 272) {               // k<4 always true; k==4 -> lane<16
                int cb   = u / 34;       // chunk of 16 channels
                int colL = u - cb * 34;  // 0..33
                int wv   = c0 + colL - 1;
                bool valid = vh && ((unsigned)wv < (unsigned)W_);
                uint4 v = make_uint4(0u, 0u, 0u, 0u);
                if (valid) {
                    const uint32_t* pc = xrow + (size_t)(cb * 16) * HW_ + wv;
                    uint32_t s;
                    s = (pc[0] >> 31)        | ((pc[HW_] >> 31) << 8)
                      | ((pc[2*HW_] >> 31) << 16) | ((pc[3*HW_] >> 31) << 24);
                    v.x = 0x01010101u + s * 0xFEu;
                    s = (pc[4*HW_] >> 31)    | ((pc[5*HW_] >> 31) << 8)
                      | ((pc[6*HW_] >> 31) << 16) | ((pc[7*HW_] >> 31) << 24);
                    v.y = 0x01010101u + s * 0xFEu;
                    s = (pc[8*HW_] >> 31)    | ((pc[9*HW_] >> 31) << 8)
                      | ((pc[10*HW_] >> 31) << 16) | ((pc[11*HW_] >> 31) << 24);
                    v.z = 0x01010101u + s * 0xFEu;
                    s = (pc[12*HW_] >> 31)   | ((pc[13*HW_] >> 31) << 8)
                      | ((pc[14*HW_] >> 31) << 16) | ((pc[15*HW_] >> 31) << 24);
                    v.w = 0x01010101u + s * 0xFEu;
                }
                actT[(rho * 34 + colL) * 8 + (cb ^ (colL & 7))] = v;
            }
        }
    }

    __syncthreads();                     // the ONLY barrier

    i32x4 acc[2][4];                     // init AFTER barrier: keeps expansion-
    #pragma unroll                       // phase register peak low
    for (int mi = 0; mi < 2; ++mi)
        #pragma unroll
        for (int j = 0; j < 4; ++j)
            #pragma unroll
            for (int e = 0; e < 4; ++e) acc[mi][j][e] = 0;

    for (int t9 = 0; t9 < 9; ++t9) {
        int nb = t9 & 1;
        if (t9 < 8) {                    // prefetch next tap's weights
            #pragma unroll
            for (int mi = 0; mi < 2; ++mi)
                #pragma unroll
                for (int ks = 0; ks < 2; ++ks)
                    aw[nb ^ 1][mi][ks] = *(const i32x4*)&wI8v[(size_t)(m0 + mi*16 + l15) * 72
                                                              + (t9 + 1) * 8 + ks * 4 + q];
        }
        int dh = t9 / 3, dw = t9 % 3;
        #pragma unroll
        for (int ks = 0; ks < 2; ++ks) {
            #pragma unroll
            for (int j = 0; j < 4; ++j) {
                int n    = j * 16 + l15;
                int colL = (n & 31) + dw;
                int rho  = (n >> 5) + dh;
                i32x4 bf = *(const i32x4*)&actT[(rho * 34 + colL) * 8 + ((ks * 4 + q) ^ (colL & 7))];
                acc[0][j] = __builtin_amdgcn_mfma_i32_16x16x64_i8(aw[nb][0][ks], bf, acc[0][j], 0, 0, 0);
                acc[1][j] = __builtin_amdgcn_mfma_i32_16x16x64_i8(aw[nb][1][ks], bf, acc[1][j], 0, 0, 0);
            }
        }
    }

    // ---- epilogue: BN + residual, coalesced 64B segments ----
    #pragma unroll
    for (int j = 0; j < 4; ++j) {
        int n = j * 16 + l15;
        int w = c0 + (n & 31);
        if (w < W_) {
            int orow = r0 + (n >> 5);
            size_t pixOff = (size_t)img * P_ * HW_ + (size_t)orow * W_ + w;
            #pragma unroll
            for (int mi = 0; mi < 2; ++mi)
                #pragma unroll
                for (int reg = 0; reg < 4; ++reg) {
                    int m = m0 + mi * 16 + q * 4 + reg;
                    size_t off = pixOff + (size_t)m * HW_;
                    out[off] = (float)acc[mi][j][reg] * sInv[m] + sB0[m] + x[off];
                }
        }
    }
}

extern "C" void kernel_launch(void* const* d_in, const int* in_sizes, int n_in,
                              void* d_out, int out_size, void* d_ws, size_t ws_size,
                              hipStream_t stream) {
    const float* x      = (const float*)d_in[0];
    const float* weight = (const float*)d_in[1];
    const float* bias   = (const float*)d_in[2];
    const float* gamma  = (const float*)d_in[3];
    const float* beta   = (const float*)d_in[4];
    const float* mean   = (const float*)d_in[5];
    const float* var    = (const float*)d_in[6];
    float* out = (float*)d_out;

    uint8_t*  ws    = (uint8_t*)d_ws;
    uint32_t* wI8   = (uint32_t*)ws;
    float*    invG  = (float*)(ws + WI8_BYTES);
    float*    b0G   = invG + P_;

    wpack_kernel<<<144, 256, 0, stream>>>(weight, bias, gamma, beta, mean, var, wI8, invG, b0G);
    bconv_kernel<<<32 * 28 * 2, 256, 0, stream>>>((const uint4*)wI8, invG, b0G, x, out);
}